// Round 3
// baseline (1211.163 us; speedup 1.0000x reference)
//
#include <hip/hip_runtime.h>

// Problem constants (fixed by reference setup_inputs)
#define BATCH 2
#define L_SEQ 768
#define NH 12
#define DH 64
#define ND 8
#define EMB 768
#define RSQRT8 0.35355339059327373f

// ws layout (floats). Total 6,046,480 floats = 24.2 MB
#define OFF_Q    0
#define OFF_K    1179648
#define OFF_V    2359296
#define OFF_L    3538944   // S0 per (bh,d,q): 147456
#define OFF_PART 3686400   // partial stats [bh*8+d][st*4+kq][q]: 2359296
#define OFF_P2   6045696   // per-(b,d,h) stat sums [bd][h][st]: 768
#define OFF_W    6046464   // weights [b][d]: 16

// ---------------------------------------------------------------------------
// K1: fused QKV projection. C = hs @ W + b, scattered to [b][h][l][64] layout.
// 64x64 tiles, 4x4 per thread, fp32 (no fp32 MFMA on CDNA4).
// ---------------------------------------------------------------------------
__global__ __launch_bounds__(256) void k1_qkv(
    const float* __restrict__ hs,
    const float* __restrict__ Wq, const float* __restrict__ bq,
    const float* __restrict__ Wk, const float* __restrict__ bk,
    const float* __restrict__ Wv, const float* __restrict__ bvp,
    float* __restrict__ qw, float* __restrict__ kw, float* __restrict__ vw)
{
    __shared__ float AsT[64][68];
    __shared__ float Bs[64][68];
    const int tid = threadIdx.x;
    const int tx = tid & 15, ty = tid >> 4;
    const int bx = blockIdx.x, by = blockIdx.y, gz = blockIdx.z;
    const float* W    = (gz == 0) ? Wq : (gz == 1 ? Wk : Wv);
    const float* bias = (gz == 0) ? bq : (gz == 1 ? bk : bvp);
    float* dst        = (gz == 0) ? qw : (gz == 1 ? kw : vw);

    const int ldc = tx * 4;

    float acc[4][4];
#pragma unroll
    for (int i = 0; i < 4; i++)
#pragma unroll
        for (int j = 0; j < 4; j++) acc[i][j] = 0.f;

    for (int k0 = 0; k0 < EMB; k0 += 64) {
        __syncthreads();
#pragma unroll
        for (int i = 0; i < 4; i++) {
            int r = ty + 16 * i;
            float4 a = *(const float4*)&hs[(size_t)(by * 64 + r) * EMB + k0 + ldc];
            AsT[ldc + 0][r] = a.x; AsT[ldc + 1][r] = a.y;
            AsT[ldc + 2][r] = a.z; AsT[ldc + 3][r] = a.w;
            *(float4*)&Bs[r][ldc] =
                *(const float4*)&W[(size_t)(k0 + r) * EMB + bx * 64 + ldc];
        }
        __syncthreads();
#pragma unroll 8
        for (int kk = 0; kk < 64; kk++) {
            float av[4], bb[4];
            *(float4*)av = *(const float4*)&AsT[kk][ty * 4];
            *(float4*)bb = *(const float4*)&Bs[kk][tx * 4];
#pragma unroll
            for (int i = 0; i < 4; i++)
#pragma unroll
                for (int j = 0; j < 4; j++)
                    acc[i][j] = fmaf(av[i], bb[j], acc[i][j]);
        }
    }

#pragma unroll
    for (int i = 0; i < 4; i++) {
        int m = by * 64 + ty * 4 + i;
        int b2 = m / L_SEQ, l = m % L_SEQ;
        float o[4];
#pragma unroll
        for (int j = 0; j < 4; j++) o[j] = acc[i][j] + bias[bx * 64 + tx * 4 + j];
        *(float4*)&dst[((size_t)(b2 * NH + bx) * L_SEQ + l) * DH + tx * 4] = *(float4*)o;
    }
}

// ---------------------------------------------------------------------------
// K2: softmax partial stats. Block = (bh, 64-q tile, k-quarter of 192).
// 4 waves x 16 q rows; lane = (qr, d); K chunk [64k][64dim] staged in LDS.
// grid 1152 -> ~4.5 blocks/CU (was 2.25).
// ---------------------------------------------------------------------------
__global__ __launch_bounds__(256) void k2_stats(
    const float* __restrict__ qw, const float* __restrict__ kw,
    const float* __restrict__ mask, float* __restrict__ part)
{
    __shared__ float k_lds[64 * 64];
    __shared__ float m_lds[64];
    const int tid = threadIdx.x;
    const int lane = tid & 63, w = tid >> 6;
    const int qr = lane >> 3, d = lane & 7;
    const int blk = blockIdx.x;
    const int kq = blk & 3;
    const int t2 = blk >> 2;            // 0..287
    const int bh = t2 / 12;
    const int q0 = (t2 % 12) * 64;
    const int b = bh / NH;
    const int qw0 = q0 + w * 16;

    float qf[2][8];
#pragma unroll
    for (int qq = 0; qq < 2; qq++) {
        const float* qp = &qw[((size_t)bh * L_SEQ + qw0 + qr + qq * 8) * DH + d * 8];
        *(float4*)&qf[qq][0] = *(const float4*)qp;
        *(float4*)&qf[qq][4] = *(const float4*)(qp + 4);
    }
    float S[2] = {0.f, 0.f}, T2[2] = {0.f, 0.f}, SL[2] = {0.f, 0.f};
    float M[2] = {-1e30f, -1e30f};

    const int kb0 = kq * 192;
    for (int c = 0; c < 3; c++) {
        const int kb = kb0 + c * 64;
        __syncthreads();
        {
            const float* src = &kw[((size_t)bh * L_SEQ + kb) * DH];
#pragma unroll
            for (int i = 0; i < 4; i++) {
                int f = tid + 256 * i;
                *(float4*)&k_lds[f * 4] = *(const float4*)&src[f * 4];
            }
            if (tid < 64) m_lds[tid] = mask[b * L_SEQ + kb + tid];
        }
        __syncthreads();
#pragma unroll 4
        for (int kk = 0; kk < 64; kk++) {
            float kv[8];
            *(float4*)&kv[0] = *(const float4*)&k_lds[kk * 64 + d * 8];
            *(float4*)&kv[4] = *(const float4*)&k_lds[kk * 64 + d * 8 + 4];
            float mval = m_lds[kk];
#pragma unroll
            for (int qq = 0; qq < 2; qq++) {
                float s = 0.f;
#pragma unroll
                for (int t = 0; t < 8; t++) s = fmaf(qf[qq][t], kv[t], s);
                s = fmaf(s, RSQRT8, mval);
                float e = __expf(s);
                S[qq] += e;
                T2[qq] = fmaf(e, e, T2[qq]);
                SL[qq] = fmaf(s, e, SL[qq]);
                M[qq] = fmaxf(M[qq], s);
            }
        }
    }
    // partials: part[((bh*8+d)*16 + st*4 + kq)*768 + q]
#pragma unroll
    for (int qq = 0; qq < 2; qq++) {
        int q = qw0 + qr + qq * 8;
        size_t base = (size_t)(bh * 8 + d) * 16;
        part[(base + 0 + kq) * 768 + q] = S[qq];
        part[(base + 4 + kq) * 768 + q] = T2[qq];
        part[(base + 8 + kq) * 768 + q] = SL[qq];
        part[(base + 12 + kq) * 768 + q] = M[qq];
    }
}

// ---------------------------------------------------------------------------
// K3a: per-(b,d,h) combine of k-quarters -> row stats -> l_arr + stat sums.
// grid 192 (one block per (b,d,h)) for latency parallelism.
// ---------------------------------------------------------------------------
__global__ __launch_bounds__(256) void k3_reduce(
    const float* __restrict__ part, float* __restrict__ l_arr,
    float* __restrict__ part2)
{
    const int bdh = blockIdx.x;         // ((b*8+d)*12+h)
    const int bd = bdh / 12, h = bdh % 12;
    const int b = bd >> 3, d = bd & 7;
    const int bh = b * NH + h;
    const int tid = threadIdx.x;
    const int lane = tid & 63, wave = tid >> 6;
    const size_t base = (size_t)(bh * 8 + d) * 16;
    float acc[4] = {0.f, 0.f, 0.f, 0.f};

    for (int q = tid; q < 768; q += 256) {
        float Sv = 0.f, T2v = 0.f, SLv = 0.f, Mv = -1e30f;
#pragma unroll
        for (int kq = 0; kq < 4; kq++) {
            Sv  += part[(base + 0 + kq) * 768 + q];
            T2v += part[(base + 4 + kq) * 768 + q];
            SLv += part[(base + 8 + kq) * 768 + q];
            Mv = fmaxf(Mv, part[(base + 12 + kq) * 768 + q]);
        }
        l_arr[(size_t)(bh * 8 + d) * 768 + q] = Sv;
        float inv = 1.0f / Sv;
        float hhi = T2v * inv * inv;
        float maxp = __expf(Mv) * inv;
        float ent = __logf(Sv) - SLv * inv;
        float var = (hhi - (1.0f / 768.0f)) * (1.0f / 767.0f);
        acc[0] += var; acc[1] += maxp; acc[2] += ent; acc[3] += hhi;
    }
    __shared__ float red[4][4];
#pragma unroll
    for (int st = 0; st < 4; st++) {
        float a = acc[st];
#pragma unroll
        for (int off = 32; off > 0; off >>= 1) a += __shfl_xor(a, off, 64);
        acc[st] = a;
    }
    if (lane == 0) {
#pragma unroll
        for (int st = 0; st < 4; st++) red[wave][st] = acc[st];
    }
    __syncthreads();
    if (tid == 0) {
#pragma unroll
        for (int st = 0; st < 4; st++)
            part2[(size_t)(bd * 12 + h) * 4 + st] =
                red[0][st] + red[1][st] + red[2][st] + red[3][st];
    }
}

// ---------------------------------------------------------------------------
// K3b: sum over h, min-max norm over d, softmax(2.5*score) -> weights[b][d].
// ---------------------------------------------------------------------------
__global__ __launch_bounds__(64) void k3_weights(
    const float* __restrict__ part2, float* __restrict__ wgt)
{
    __shared__ float stats_l[64];       // [b][d][st]
    const int tid = threadIdx.x;
    {
        const int bd = tid >> 2, st = tid & 3;
        float s = 0.f;
#pragma unroll
        for (int h = 0; h < 12; h++) s += part2[(size_t)(bd * 12 + h) * 4 + st];
        stats_l[tid] = s * (1.0f / 9216.0f);
    }
    __syncthreads();
    if (tid == 0) {
        for (int b = 0; b < BATCH; b++) {
            float v[4][8];
            for (int st = 0; st < 4; st++)
                for (int d = 0; d < 8; d++) v[st][d] = stats_l[(b * 8 + d) * 4 + st];
            float nrm[4][8];
            for (int st = 0; st < 4; st++) {
                float mn = v[st][0], mx = v[st][0];
                for (int d = 1; d < 8; d++) { mn = fminf(mn, v[st][d]); mx = fmaxf(mx, v[st][d]); }
                float rng = fmaxf(mx - mn, 1e-12f);
                for (int d = 0; d < 8; d++) nrm[st][d] = (v[st][d] - mn) / rng;
            }
            float sc[8];
            for (int d = 0; d < 8; d++)
                sc[d] = 0.5f * nrm[0][d] + 0.3f * nrm[1][d] + 0.2f * nrm[3][d] - 0.4f * nrm[2][d];
            float m = 2.5f * sc[0];
            for (int d = 1; d < 8; d++) m = fmaxf(m, 2.5f * sc[d]);
            float e8[8]; float ssum = 0.f;
            for (int d = 0; d < 8; d++) { e8[d] = __expf(2.5f * sc[d] - m); ssum += e8[d]; }
            for (int d = 0; d < 8; d++) wgt[b * ND + d] = e8[d] / ssum;
        }
    }
}

// ---------------------------------------------------------------------------
// K4: attn4 + ctx. Block = (bh, 64-q tile, k-eighth of 96); 32-kk staged
// tiles (LDS 25.3KB -> 6 blocks/CU); grid 2304 (~9/CU, VGPR-capped at 16
// waves/CU via launch_bounds(256,4)). kk batched x4 for ILP across the
// exp->butterfly dependency chain. ctx combined via 8 atomicAdds/elem.
// ---------------------------------------------------------------------------
__global__ __launch_bounds__(256, 4) void k4_out(
    const float* __restrict__ qw, const float* __restrict__ kw,
    const float* __restrict__ vw, const float* __restrict__ mask,
    const float* __restrict__ l_arr, const float* __restrict__ wgt,
    float* __restrict__ out_ctx, float* __restrict__ out_a4)
{
    __shared__ float k_lds[32 * 64];
    __shared__ float v_lds[32 * 64];
    __shared__ float a4_lds[4][16 * 36];
    __shared__ float m_lds[32];
    const int tid = threadIdx.x;
    const int lane = tid & 63, w = tid >> 6;
    const int qr = lane >> 3, d = lane & 7;
    const int blk = blockIdx.x;
    const int kq = blk & 7;
    const int t2 = blk >> 3;
    const int bh = t2 / 12;
    const int q0 = (t2 % 12) * 64;
    const int b = bh / NH, h = bh % NH;
    const int qw0 = q0 + w * 16;

    float qf[2][8];
    float c0[2];
#pragma unroll
    for (int qq = 0; qq < 2; qq++) {
        int row = qw0 + qr + qq * 8;
        const float* qp = &qw[((size_t)bh * L_SEQ + row) * DH + d * 8];
        *(float4*)&qf[qq][0] = *(const float4*)qp;
        *(float4*)&qf[qq][4] = *(const float4*)(qp + 4);
        c0[qq] = wgt[b * ND + d] / l_arr[(size_t)(bh * 8 + d) * 768 + row];
    }
    float ctx[2][8];
#pragma unroll
    for (int qq = 0; qq < 2; qq++)
#pragma unroll
        for (int t = 0; t < 8; t++) ctx[qq][t] = 0.f;

    const int kb0 = kq * 96;
    for (int c = 0; c < 3; c++) {
        const int kb = kb0 + c * 32;
        __syncthreads();
        {
            const float* ksrc = &kw[((size_t)bh * L_SEQ + kb) * DH];
            const float* vsrc = &vw[((size_t)bh * L_SEQ + kb) * DH];
#pragma unroll
            for (int i = 0; i < 2; i++) {
                int f = tid + 256 * i;
                *(float4*)&k_lds[f * 4] = *(const float4*)&ksrc[f * 4];
                *(float4*)&v_lds[f * 4] = *(const float4*)&vsrc[f * 4];
            }
            if (tid < 32) m_lds[tid] = mask[b * L_SEQ + kb + tid];
        }
        __syncthreads();

#pragma unroll
        for (int kk4 = 0; kk4 < 32; kk4 += 4) {
            float a4v[4][2];
            // 8 independent score->exp chains
#pragma unroll
            for (int u = 0; u < 4; u++) {
                int kk = kk4 + u;
                float kv[8];
                *(float4*)&kv[0] = *(const float4*)&k_lds[kk * 64 + d * 8];
                *(float4*)&kv[4] = *(const float4*)&k_lds[kk * 64 + d * 8 + 4];
                float mval = m_lds[kk];
#pragma unroll
                for (int qq = 0; qq < 2; qq++) {
                    float s = 0.f;
#pragma unroll
                    for (int t = 0; t < 8; t++) s = fmaf(qf[qq][t], kv[t], s);
                    s = fmaf(s, RSQRT8, mval);
                    a4v[u][qq] = c0[qq] * __expf(s);
                }
            }
            // 8 independent 8-lane butterflies (sum over d)
#pragma unroll
            for (int u = 0; u < 4; u++)
#pragma unroll
                for (int qq = 0; qq < 2; qq++) {
                    float a = a4v[u][qq];
                    a += __shfl_xor(a, 1, 64);
                    a += __shfl_xor(a, 2, 64);
                    a += __shfl_xor(a, 4, 64);
                    a4v[u][qq] = a;
                }
            // ctx accumulation + a4 tile collect
#pragma unroll
            for (int u = 0; u < 4; u++) {
                int kk = kk4 + u;
                float vv[8];
                *(float4*)&vv[0] = *(const float4*)&v_lds[kk * 64 + d * 8];
                *(float4*)&vv[4] = *(const float4*)&v_lds[kk * 64 + d * 8 + 4];
#pragma unroll
                for (int qq = 0; qq < 2; qq++)
#pragma unroll
                    for (int t = 0; t < 8; t++)
                        ctx[qq][t] = fmaf(a4v[u][qq], vv[t], ctx[qq][t]);
                if (d < 2)
                    a4_lds[w][(qr + d * 8) * 36 + kk] = (d == 0) ? a4v[u][0] : a4v[u][1];
            }
        }
        // coalesced a4 drain (per-wave tile; same-wave RAW -> lgkmcnt only)
#pragma unroll
        for (int i = 0; i < 2; i++) {
            int f = lane + 64 * i;
            int row = f >> 3, c4 = (f & 7) * 4;
            *(float4*)&out_a4[((size_t)bh * L_SEQ + qw0 + row) * L_SEQ + kb + c4] =
                *(float4*)&a4_lds[w][row * 36 + c4];
        }
    }
#pragma unroll
    for (int qq = 0; qq < 2; qq++) {
        int row = qw0 + qr + qq * 8;
#pragma unroll
        for (int t = 0; t < 8; t++)
            atomicAdd(&out_ctx[((size_t)b * L_SEQ + row) * EMB + h * DH + d * 8 + t],
                      ctx[qq][t]);
    }
}

// ---------------------------------------------------------------------------
extern "C" void kernel_launch(void* const* d_in, const int* in_sizes, int n_in,
                              void* d_out, int out_size, void* d_ws, size_t ws_size,
                              hipStream_t stream)
{
    const float* hs   = (const float*)d_in[0];
    const float* mask = (const float*)d_in[1];
    const float* Wq   = (const float*)d_in[2];
    const float* bq   = (const float*)d_in[3];
    const float* Wk   = (const float*)d_in[4];
    const float* bk   = (const float*)d_in[5];
    const float* Wv   = (const float*)d_in[6];
    const float* bv   = (const float*)d_in[7];

    float* ws = (float*)d_ws;
    float* qw = ws + OFF_Q;
    float* kw = ws + OFF_K;
    float* vw = ws + OFF_V;
    float* l_arr = ws + OFF_L;
    float* part  = ws + OFF_PART;
    float* part2 = ws + OFF_P2;
    float* wgt   = ws + OFF_W;

    float* out_ctx = (float*)d_out;                                  // [B, L, 768]
    float* out_a4  = (float*)d_out + (size_t)BATCH * L_SEQ * EMB;    // [B, H, L, L]

    hipMemsetAsync(out_ctx, 0, (size_t)BATCH * L_SEQ * EMB * sizeof(float), stream);
    k1_qkv<<<dim3(12, 24, 3), 256, 0, stream>>>(hs, Wq, bq, Wk, bk, Wv, bv, qw, kw, vw);
    k2_stats<<<dim3(1152), 256, 0, stream>>>(qw, kw, mask, part);
    k3_reduce<<<dim3(192), 256, 0, stream>>>(part, l_arr, part2);
    k3_weights<<<dim3(1), 64, 0, stream>>>(part2, wgt);
    k4_out<<<dim3(2304), 256, 0, stream>>>(qw, kw, vw, mask, l_arr, wgt, out_ctx, out_a4);
}

// Round 4
// 458.496 us; speedup vs baseline: 2.6416x; 2.6416x over previous
//
#include <hip/hip_runtime.h>

// Problem constants (fixed by reference setup_inputs)
#define BATCH 2
#define L_SEQ 768
#define NH 12
#define DH 64
#define ND 8
#define EMB 768
#define RSQRT8 0.35355339059327373f

// ws layout (floats). Total 6,046,480 floats = 24.2 MB
#define OFF_Q    0
#define OFF_K    1179648
#define OFF_V    2359296
#define OFF_L    3538944   // S0 per (bh,d,q): 147456
#define OFF_PART 3686400   // partial stats [bh*8+d][st*4+kq][q]: 2359296
#define OFF_P2   6045696   // per-(b,d,h) stat sums [bd][h][st]: 768
#define OFF_W    6046464   // weights [b][d]: 16

// ---------------------------------------------------------------------------
// K1: fused QKV projection. C = hs @ W + b, scattered to [b][h][l][64] layout.
// 64x64 tiles, 4x4 per thread, fp32 (no fp32 MFMA on CDNA4).
// ---------------------------------------------------------------------------
__global__ __launch_bounds__(256) void k1_qkv(
    const float* __restrict__ hs,
    const float* __restrict__ Wq, const float* __restrict__ bq,
    const float* __restrict__ Wk, const float* __restrict__ bk,
    const float* __restrict__ Wv, const float* __restrict__ bvp,
    float* __restrict__ qw, float* __restrict__ kw, float* __restrict__ vw)
{
    __shared__ float AsT[64][68];
    __shared__ float Bs[64][68];
    const int tid = threadIdx.x;
    const int tx = tid & 15, ty = tid >> 4;
    const int bx = blockIdx.x, by = blockIdx.y, gz = blockIdx.z;
    const float* W    = (gz == 0) ? Wq : (gz == 1 ? Wk : Wv);
    const float* bias = (gz == 0) ? bq : (gz == 1 ? bk : bvp);
    float* dst        = (gz == 0) ? qw : (gz == 1 ? kw : vw);

    const int ldc = tx * 4;

    float acc[4][4];
#pragma unroll
    for (int i = 0; i < 4; i++)
#pragma unroll
        for (int j = 0; j < 4; j++) acc[i][j] = 0.f;

    for (int k0 = 0; k0 < EMB; k0 += 64) {
        __syncthreads();
#pragma unroll
        for (int i = 0; i < 4; i++) {
            int r = ty + 16 * i;
            float4 a = *(const float4*)&hs[(size_t)(by * 64 + r) * EMB + k0 + ldc];
            AsT[ldc + 0][r] = a.x; AsT[ldc + 1][r] = a.y;
            AsT[ldc + 2][r] = a.z; AsT[ldc + 3][r] = a.w;
            *(float4*)&Bs[r][ldc] =
                *(const float4*)&W[(size_t)(k0 + r) * EMB + bx * 64 + ldc];
        }
        __syncthreads();
#pragma unroll 8
        for (int kk = 0; kk < 64; kk++) {
            float av[4], bb[4];
            *(float4*)av = *(const float4*)&AsT[kk][ty * 4];
            *(float4*)bb = *(const float4*)&Bs[kk][tx * 4];
#pragma unroll
            for (int i = 0; i < 4; i++)
#pragma unroll
                for (int j = 0; j < 4; j++)
                    acc[i][j] = fmaf(av[i], bb[j], acc[i][j]);
        }
    }

#pragma unroll
    for (int i = 0; i < 4; i++) {
        int m = by * 64 + ty * 4 + i;
        int b2 = m / L_SEQ, l = m % L_SEQ;
        float o[4];
#pragma unroll
        for (int j = 0; j < 4; j++) o[j] = acc[i][j] + bias[bx * 64 + tx * 4 + j];
        *(float4*)&dst[((size_t)(b2 * NH + bx) * L_SEQ + l) * DH + tx * 4] = *(float4*)o;
    }
}

// ---------------------------------------------------------------------------
// K2: softmax partial stats. Block = (bh, 64-q tile, k-quarter of 192).
// 4 waves x 16 q rows; lane = (qr, d); K chunk [64k][64dim] staged in LDS.
// ---------------------------------------------------------------------------
__global__ __launch_bounds__(256) void k2_stats(
    const float* __restrict__ qw, const float* __restrict__ kw,
    const float* __restrict__ mask, float* __restrict__ part)
{
    __shared__ float k_lds[64 * 64];
    __shared__ float m_lds[64];
    const int tid = threadIdx.x;
    const int lane = tid & 63, w = tid >> 6;
    const int qr = lane >> 3, d = lane & 7;
    const int blk = blockIdx.x;
    const int kq = blk & 3;
    const int t2 = blk >> 2;            // 0..287
    const int bh = t2 / 12;
    const int q0 = (t2 % 12) * 64;
    const int b = bh / NH;
    const int qw0 = q0 + w * 16;

    float qf[2][8];
#pragma unroll
    for (int qq = 0; qq < 2; qq++) {
        const float* qp = &qw[((size_t)bh * L_SEQ + qw0 + qr + qq * 8) * DH + d * 8];
        *(float4*)&qf[qq][0] = *(const float4*)qp;
        *(float4*)&qf[qq][4] = *(const float4*)(qp + 4);
    }
    float S[2] = {0.f, 0.f}, T2[2] = {0.f, 0.f}, SL[2] = {0.f, 0.f};
    float M[2] = {-1e30f, -1e30f};

    const int kb0 = kq * 192;
    for (int c = 0; c < 3; c++) {
        const int kb = kb0 + c * 64;
        __syncthreads();
        {
            const float* src = &kw[((size_t)bh * L_SEQ + kb) * DH];
#pragma unroll
            for (int i = 0; i < 4; i++) {
                int f = tid + 256 * i;
                *(float4*)&k_lds[f * 4] = *(const float4*)&src[f * 4];
            }
            if (tid < 64) m_lds[tid] = mask[b * L_SEQ + kb + tid];
        }
        __syncthreads();
#pragma unroll 4
        for (int kk = 0; kk < 64; kk++) {
            float kv[8];
            *(float4*)&kv[0] = *(const float4*)&k_lds[kk * 64 + d * 8];
            *(float4*)&kv[4] = *(const float4*)&k_lds[kk * 64 + d * 8 + 4];
            float mval = m_lds[kk];
#pragma unroll
            for (int qq = 0; qq < 2; qq++) {
                float s = 0.f;
#pragma unroll
                for (int t = 0; t < 8; t++) s = fmaf(qf[qq][t], kv[t], s);
                s = fmaf(s, RSQRT8, mval);
                float e = __expf(s);
                S[qq] += e;
                T2[qq] = fmaf(e, e, T2[qq]);
                SL[qq] = fmaf(s, e, SL[qq]);
                M[qq] = fmaxf(M[qq], s);
            }
        }
    }
#pragma unroll
    for (int qq = 0; qq < 2; qq++) {
        int q = qw0 + qr + qq * 8;
        size_t base = (size_t)(bh * 8 + d) * 16;
        part[(base + 0 + kq) * 768 + q] = S[qq];
        part[(base + 4 + kq) * 768 + q] = T2[qq];
        part[(base + 8 + kq) * 768 + q] = SL[qq];
        part[(base + 12 + kq) * 768 + q] = M[qq];
    }
}

// ---------------------------------------------------------------------------
// K3a: per-(b,d,h) combine of k-quarters -> row stats -> l_arr + stat sums.
// ---------------------------------------------------------------------------
__global__ __launch_bounds__(256) void k3_reduce(
    const float* __restrict__ part, float* __restrict__ l_arr,
    float* __restrict__ part2)
{
    const int bdh = blockIdx.x;         // ((b*8+d)*12+h)
    const int bd = bdh / 12, h = bdh % 12;
    const int b = bd >> 3, d = bd & 7;
    const int bh = b * NH + h;
    const int tid = threadIdx.x;
    const int lane = tid & 63, wave = tid >> 6;
    const size_t base = (size_t)(bh * 8 + d) * 16;
    float acc[4] = {0.f, 0.f, 0.f, 0.f};

    for (int q = tid; q < 768; q += 256) {
        float Sv = 0.f, T2v = 0.f, SLv = 0.f, Mv = -1e30f;
#pragma unroll
        for (int kq = 0; kq < 4; kq++) {
            Sv  += part[(base + 0 + kq) * 768 + q];
            T2v += part[(base + 4 + kq) * 768 + q];
            SLv += part[(base + 8 + kq) * 768 + q];
            Mv = fmaxf(Mv, part[(base + 12 + kq) * 768 + q]);
        }
        l_arr[(size_t)(bh * 8 + d) * 768 + q] = Sv;
        float inv = 1.0f / Sv;
        float hhi = T2v * inv * inv;
        float maxp = __expf(Mv) * inv;
        float ent = __logf(Sv) - SLv * inv;
        float var = (hhi - (1.0f / 768.0f)) * (1.0f / 767.0f);
        acc[0] += var; acc[1] += maxp; acc[2] += ent; acc[3] += hhi;
    }
    __shared__ float red[4][4];
#pragma unroll
    for (int st = 0; st < 4; st++) {
        float a = acc[st];
#pragma unroll
        for (int off = 32; off > 0; off >>= 1) a += __shfl_xor(a, off, 64);
        acc[st] = a;
    }
    if (lane == 0) {
#pragma unroll
        for (int st = 0; st < 4; st++) red[wave][st] = acc[st];
    }
    __syncthreads();
    if (tid == 0) {
#pragma unroll
        for (int st = 0; st < 4; st++)
            part2[(size_t)(bd * 12 + h) * 4 + st] =
                red[0][st] + red[1][st] + red[2][st] + red[3][st];
    }
}

// ---------------------------------------------------------------------------
// K3b: sum over h, min-max norm over d, softmax(2.5*score) -> weights[b][d].
// ---------------------------------------------------------------------------
__global__ __launch_bounds__(64) void k3_weights(
    const float* __restrict__ part2, float* __restrict__ wgt)
{
    __shared__ float stats_l[64];       // [b][d][st]
    const int tid = threadIdx.x;
    {
        const int bd = tid >> 2, st = tid & 3;
        float s = 0.f;
#pragma unroll
        for (int h = 0; h < 12; h++) s += part2[(size_t)(bd * 12 + h) * 4 + st];
        stats_l[tid] = s * (1.0f / 9216.0f);
    }
    __syncthreads();
    if (tid == 0) {
        for (int b = 0; b < BATCH; b++) {
            float v[4][8];
            for (int st = 0; st < 4; st++)
                for (int d = 0; d < 8; d++) v[st][d] = stats_l[(b * 8 + d) * 4 + st];
            float nrm[4][8];
            for (int st = 0; st < 4; st++) {
                float mn = v[st][0], mx = v[st][0];
                for (int d = 1; d < 8; d++) { mn = fminf(mn, v[st][d]); mx = fmaxf(mx, v[st][d]); }
                float rng = fmaxf(mx - mn, 1e-12f);
                for (int d = 0; d < 8; d++) nrm[st][d] = (v[st][d] - mn) / rng;
            }
            float sc[8];
            for (int d = 0; d < 8; d++)
                sc[d] = 0.5f * nrm[0][d] + 0.3f * nrm[1][d] + 0.2f * nrm[3][d] - 0.4f * nrm[2][d];
            float m = 2.5f * sc[0];
            for (int d = 1; d < 8; d++) m = fmaxf(m, 2.5f * sc[d]);
            float e8[8]; float ssum = 0.f;
            for (int d = 0; d < 8; d++) { e8[d] = __expf(2.5f * sc[d] - m); ssum += e8[d]; }
            for (int d = 0; d < 8; d++) wgt[b * ND + d] = e8[d] / ssum;
        }
    }
}

// ---------------------------------------------------------------------------
// K4: attn4 ONLY (ctx moved to K5 -> zero atomics, zero cross-block combine;
// round-3 lesson: concurrent cross-XCD atomics to shared lines caused a 16x
// HBM write storm). Block = (bh, 64-q tile, k-quarter of 192), 32-kk staged
// K tiles. LDS 17.3KB (9 blocks/CU cap), grid 1152, no VGPR cap.
// ---------------------------------------------------------------------------
__global__ __launch_bounds__(256) void k4_attn(
    const float* __restrict__ qw, const float* __restrict__ kw,
    const float* __restrict__ mask,
    const float* __restrict__ l_arr, const float* __restrict__ wgt,
    float* __restrict__ out_a4)
{
    __shared__ float k_lds[32 * 64];
    __shared__ float a4_lds[4][16 * 36];
    __shared__ float m_lds[32];
    const int tid = threadIdx.x;
    const int lane = tid & 63, w = tid >> 6;
    const int qr = lane >> 3, d = lane & 7;
    const int blk = blockIdx.x;
    const int kq = blk & 3;
    const int t2 = blk >> 2;
    const int bh = t2 / 12;
    const int q0 = (t2 % 12) * 64;
    const int b = bh / NH;
    const int qw0 = q0 + w * 16;

    float qf[2][8];
    float c0[2];
#pragma unroll
    for (int qq = 0; qq < 2; qq++) {
        int row = qw0 + qr + qq * 8;
        const float* qp = &qw[((size_t)bh * L_SEQ + row) * DH + d * 8];
        *(float4*)&qf[qq][0] = *(const float4*)qp;
        *(float4*)&qf[qq][4] = *(const float4*)(qp + 4);
        c0[qq] = wgt[b * ND + d] / l_arr[(size_t)(bh * 8 + d) * 768 + row];
    }

    const int kb0 = kq * 192;
    for (int c = 0; c < 6; c++) {
        const int kb = kb0 + c * 32;
        __syncthreads();
        {
            const float* ksrc = &kw[((size_t)bh * L_SEQ + kb) * DH];
#pragma unroll
            for (int i = 0; i < 2; i++) {
                int f = tid + 256 * i;
                *(float4*)&k_lds[f * 4] = *(const float4*)&ksrc[f * 4];
            }
            if (tid < 32) m_lds[tid] = mask[b * L_SEQ + kb + tid];
        }
        __syncthreads();

#pragma unroll
        for (int kk2 = 0; kk2 < 32; kk2 += 2) {
            float a4v[2][2];
            // 4 independent score->exp chains (ILP across the exp latency)
#pragma unroll
            for (int u = 0; u < 2; u++) {
                int kk = kk2 + u;
                float kv[8];
                *(float4*)&kv[0] = *(const float4*)&k_lds[kk * 64 + d * 8];
                *(float4*)&kv[4] = *(const float4*)&k_lds[kk * 64 + d * 8 + 4];
                float mval = m_lds[kk];
#pragma unroll
                for (int qq = 0; qq < 2; qq++) {
                    float s = 0.f;
#pragma unroll
                    for (int t = 0; t < 8; t++) s = fmaf(qf[qq][t], kv[t], s);
                    s = fmaf(s, RSQRT8, mval);
                    a4v[u][qq] = c0[qq] * __expf(s);
                }
            }
            // 4 independent 8-lane butterflies (sum over d)
#pragma unroll
            for (int u = 0; u < 2; u++)
#pragma unroll
                for (int qq = 0; qq < 2; qq++) {
                    float a = a4v[u][qq];
                    a += __shfl_xor(a, 1, 64);
                    a += __shfl_xor(a, 2, 64);
                    a += __shfl_xor(a, 4, 64);
                    a4v[u][qq] = a;
                }
#pragma unroll
            for (int u = 0; u < 2; u++) {
                int kk = kk2 + u;
                if (d < 2)
                    a4_lds[w][(qr + d * 8) * 36 + kk] = (d == 0) ? a4v[u][0] : a4v[u][1];
            }
        }
        // coalesced a4 drain (per-wave tile; same-wave RAW -> lgkmcnt only)
#pragma unroll
        for (int i = 0; i < 2; i++) {
            int f = lane + 64 * i;
            int row = f >> 3, c4 = (f & 7) * 4;
            *(float4*)&out_a4[((size_t)bh * L_SEQ + qw0 + row) * L_SEQ + kb + c4] =
                *(float4*)&a4_lds[w][row * 36 + c4];
        }
    }
}

// ---------------------------------------------------------------------------
// K5: ctx = attn4 @ V, reading attn4 back from d_out (L2/LLC-resident).
// Block = (bh, 32-q tile); 4 waves x 8 rows; lane = dh column.
// attn4 row segments are wave-uniform addresses -> scalar/broadcast loads
// (avoids an LDS round-trip that would be ds_read_b128-throughput-bound).
// V staged transposed in LDS, lane-indexed b128 (2-way alias = free).
// Writes out_ctx exactly once (no memset, no atomics).
// ---------------------------------------------------------------------------
__global__ __launch_bounds__(256) void k5_ctx(
    const float* __restrict__ vw, const float* __restrict__ out_a4,
    float* __restrict__ out_ctx)
{
    __shared__ float v_ldsT[64 * 68];   // [dh][kk], pad 68
    const int tid = threadIdx.x;
    const int lane = tid & 63, w = tid >> 6;
    const int blk = blockIdx.x;         // bh*24 + qtile
    const int bh = blk / 24;
    const int q0 = (blk % 24) * 32;
    const int b = bh / NH, h = bh % NH;
    const int r0 = w * 8;

    float ctx[8];
#pragma unroll
    for (int r = 0; r < 8; r++) ctx[r] = 0.f;

    for (int c = 0; c < 12; c++) {
        const int kb = c * 64;
        __syncthreads();
        {   // stage V chunk transposed: v_ldsT[dh][kk] = V[kb+kk][dh]
#pragma unroll
            for (int i = 0; i < 4; i++) {
                int f = tid + 256 * i;          // 0..1023
                int kk = f >> 4, c4 = (f & 15) * 4;
                float4 v = *(const float4*)&vw[((size_t)bh * L_SEQ + kb + kk) * DH + c4];
                v_ldsT[(c4 + 0) * 68 + kk] = v.x;
                v_ldsT[(c4 + 1) * 68 + kk] = v.y;
                v_ldsT[(c4 + 2) * 68 + kk] = v.z;
                v_ldsT[(c4 + 3) * 68 + kk] = v.w;
            }
        }
        __syncthreads();
#pragma unroll 4
        for (int kk4 = 0; kk4 < 16; kk4++) {
            float4 vv = *(const float4*)&v_ldsT[lane * 68 + kk4 * 4];
#pragma unroll
            for (int r = 0; r < 8; r++) {
                // wave-uniform address -> scalar/broadcast load
                float4 a = *(const float4*)&out_a4[
                    ((size_t)bh * L_SEQ + q0 + r0 + r) * L_SEQ + kb + kk4 * 4];
                ctx[r] = fmaf(a.x, vv.x, ctx[r]);
                ctx[r] = fmaf(a.y, vv.y, ctx[r]);
                ctx[r] = fmaf(a.z, vv.z, ctx[r]);
                ctx[r] = fmaf(a.w, vv.w, ctx[r]);
            }
        }
    }
#pragma unroll
    for (int r = 0; r < 8; r++)
        out_ctx[((size_t)b * L_SEQ + q0 + r0 + r) * EMB + h * DH + lane] = ctx[r];
}

// ---------------------------------------------------------------------------
extern "C" void kernel_launch(void* const* d_in, const int* in_sizes, int n_in,
                              void* d_out, int out_size, void* d_ws, size_t ws_size,
                              hipStream_t stream)
{
    const float* hs   = (const float*)d_in[0];
    const float* mask = (const float*)d_in[1];
    const float* Wq   = (const float*)d_in[2];
    const float* bq   = (const float*)d_in[3];
    const float* Wk   = (const float*)d_in[4];
    const float* bk   = (const float*)d_in[5];
    const float* Wv   = (const float*)d_in[6];
    const float* bv   = (const float*)d_in[7];

    float* ws = (float*)d_ws;
    float* qw = ws + OFF_Q;
    float* kw = ws + OFF_K;
    float* vw = ws + OFF_V;
    float* l_arr = ws + OFF_L;
    float* part  = ws + OFF_PART;
    float* part2 = ws + OFF_P2;
    float* wgt   = ws + OFF_W;

    float* out_ctx = (float*)d_out;                                  // [B, L, 768]
    float* out_a4  = (float*)d_out + (size_t)BATCH * L_SEQ * EMB;    // [B, H, L, L]

    k1_qkv<<<dim3(12, 24, 3), 256, 0, stream>>>(hs, Wq, bq, Wk, bk, Wv, bv, qw, kw, vw);
    k2_stats<<<dim3(1152), 256, 0, stream>>>(qw, kw, mask, part);
    k3_reduce<<<dim3(192), 256, 0, stream>>>(part, l_arr, part2);
    k3_weights<<<dim3(1), 64, 0, stream>>>(part2, wgt);
    k4_attn<<<dim3(1152), 256, 0, stream>>>(qw, kw, mask, l_arr, wgt, out_a4);
    k5_ctx<<<dim3(576), 256, 0, stream>>>(vw, out_a4, out_ctx);
}

// Round 6
// 446.567 us; speedup vs baseline: 2.7122x; 1.0267x over previous
//
#include <hip/hip_runtime.h>

// Problem constants (fixed by reference setup_inputs)
#define BATCH 2
#define L_SEQ 768
#define NH 12
#define DH 64
#define ND 8
#define EMB 768
#define RSQRT8 0.35355339059327373f

// ws layout (floats). Total 6,046,480 floats = 24.2 MB
#define OFF_Q    0
#define OFF_K    1179648
#define OFF_V    2359296
#define OFF_L    3538944   // S0 per (bh,d,q): 147456
#define OFF_PART 3686400   // partial stats [bh*8+d][st*4+kq][q]: 2359296
#define OFF_P2   6045696   // per-(b,d,h) stat sums [bd][h][st]: 768
#define OFF_W    6046464   // weights [b][d]: 16

// ---------------------------------------------------------------------------
// K1: fused QKV projection. C = hs @ W + b, scattered to [b][h][l][64] layout.
// 64x64 tiles, 4x4 per thread, fp32 (no fp32 MFMA on CDNA4).
// ---------------------------------------------------------------------------
__global__ __launch_bounds__(256) void k1_qkv(
    const float* __restrict__ hs,
    const float* __restrict__ Wq, const float* __restrict__ bq,
    const float* __restrict__ Wk, const float* __restrict__ bk,
    const float* __restrict__ Wv, const float* __restrict__ bvp,
    float* __restrict__ qw, float* __restrict__ kw, float* __restrict__ vw)
{
    __shared__ float AsT[64][68];
    __shared__ float Bs[64][68];
    const int tid = threadIdx.x;
    const int tx = tid & 15, ty = tid >> 4;
    const int bx = blockIdx.x, by = blockIdx.y, gz = blockIdx.z;
    const float* W    = (gz == 0) ? Wq : (gz == 1 ? Wk : Wv);
    const float* bias = (gz == 0) ? bq : (gz == 1 ? bk : bvp);
    float* dst        = (gz == 0) ? qw : (gz == 1 ? kw : vw);

    const int ldc = tx * 4;

    float acc[4][4];
#pragma unroll
    for (int i = 0; i < 4; i++)
#pragma unroll
        for (int j = 0; j < 4; j++) acc[i][j] = 0.f;

    for (int k0 = 0; k0 < EMB; k0 += 64) {
        __syncthreads();
#pragma unroll
        for (int i = 0; i < 4; i++) {
            int r = ty + 16 * i;
            float4 a = *(const float4*)&hs[(size_t)(by * 64 + r) * EMB + k0 + ldc];
            AsT[ldc + 0][r] = a.x; AsT[ldc + 1][r] = a.y;
            AsT[ldc + 2][r] = a.z; AsT[ldc + 3][r] = a.w;
            *(float4*)&Bs[r][ldc] =
                *(const float4*)&W[(size_t)(k0 + r) * EMB + bx * 64 + ldc];
        }
        __syncthreads();
#pragma unroll 8
        for (int kk = 0; kk < 64; kk++) {
            float av[4], bb[4];
            *(float4*)av = *(const float4*)&AsT[kk][ty * 4];
            *(float4*)bb = *(const float4*)&Bs[kk][tx * 4];
#pragma unroll
            for (int i = 0; i < 4; i++)
#pragma unroll
                for (int j = 0; j < 4; j++)
                    acc[i][j] = fmaf(av[i], bb[j], acc[i][j]);
        }
    }

#pragma unroll
    for (int i = 0; i < 4; i++) {
        int m = by * 64 + ty * 4 + i;
        int b2 = m / L_SEQ, l = m % L_SEQ;
        float o[4];
#pragma unroll
        for (int j = 0; j < 4; j++) o[j] = acc[i][j] + bias[bx * 64 + tx * 4 + j];
        *(float4*)&dst[((size_t)(b2 * NH + bx) * L_SEQ + l) * DH + tx * 4] = *(float4*)o;
    }
}

// ---------------------------------------------------------------------------
// K2: softmax partial stats. Block = (bh, 64-q tile, k-quarter of 192).
// 4 waves x 16 q rows; lane = (qr, d); K chunk [64k][64dim] staged in LDS.
// ---------------------------------------------------------------------------
__global__ __launch_bounds__(256) void k2_stats(
    const float* __restrict__ qw, const float* __restrict__ kw,
    const float* __restrict__ mask, float* __restrict__ part)
{
    __shared__ float k_lds[64 * 64];
    __shared__ float m_lds[64];
    const int tid = threadIdx.x;
    const int lane = tid & 63, w = tid >> 6;
    const int qr = lane >> 3, d = lane & 7;
    const int blk = blockIdx.x;
    const int kq = blk & 3;
    const int t2 = blk >> 2;            // 0..287
    const int bh = t2 / 12;
    const int q0 = (t2 % 12) * 64;
    const int b = bh / NH;
    const int qw0 = q0 + w * 16;

    float qf[2][8];
#pragma unroll
    for (int qq = 0; qq < 2; qq++) {
        const float* qp = &qw[((size_t)bh * L_SEQ + qw0 + qr + qq * 8) * DH + d * 8];
        *(float4*)&qf[qq][0] = *(const float4*)qp;
        *(float4*)&qf[qq][4] = *(const float4*)(qp + 4);
    }
    float S[2] = {0.f, 0.f}, T2[2] = {0.f, 0.f}, SL[2] = {0.f, 0.f};
    float M[2] = {-1e30f, -1e30f};

    const int kb0 = kq * 192;
    for (int c = 0; c < 3; c++) {
        const int kb = kb0 + c * 64;
        __syncthreads();
        {
            const float* src = &kw[((size_t)bh * L_SEQ + kb) * DH];
#pragma unroll
            for (int i = 0; i < 4; i++) {
                int f = tid + 256 * i;
                *(float4*)&k_lds[f * 4] = *(const float4*)&src[f * 4];
            }
            if (tid < 64) m_lds[tid] = mask[b * L_SEQ + kb + tid];
        }
        __syncthreads();
#pragma unroll 4
        for (int kk = 0; kk < 64; kk++) {
            float kv[8];
            *(float4*)&kv[0] = *(const float4*)&k_lds[kk * 64 + d * 8];
            *(float4*)&kv[4] = *(const float4*)&k_lds[kk * 64 + d * 8 + 4];
            float mval = m_lds[kk];
#pragma unroll
            for (int qq = 0; qq < 2; qq++) {
                float s = 0.f;
#pragma unroll
                for (int t = 0; t < 8; t++) s = fmaf(qf[qq][t], kv[t], s);
                s = fmaf(s, RSQRT8, mval);
                float e = __expf(s);
                S[qq] += e;
                T2[qq] = fmaf(e, e, T2[qq]);
                SL[qq] = fmaf(s, e, SL[qq]);
                M[qq] = fmaxf(M[qq], s);
            }
        }
    }
#pragma unroll
    for (int qq = 0; qq < 2; qq++) {
        int q = qw0 + qr + qq * 8;
        size_t base = (size_t)(bh * 8 + d) * 16;
        part[(base + 0 + kq) * 768 + q] = S[qq];
        part[(base + 4 + kq) * 768 + q] = T2[qq];
        part[(base + 8 + kq) * 768 + q] = SL[qq];
        part[(base + 12 + kq) * 768 + q] = M[qq];
    }
}

// ---------------------------------------------------------------------------
// K3a: per-(b,d,h) combine of k-quarters -> row stats -> l_arr + stat sums.
// ---------------------------------------------------------------------------
__global__ __launch_bounds__(256) void k3_reduce(
    const float* __restrict__ part, float* __restrict__ l_arr,
    float* __restrict__ part2)
{
    const int bdh = blockIdx.x;         // ((b*8+d)*12+h)
    const int bd = bdh / 12, h = bdh % 12;
    const int b = bd >> 3, d = bd & 7;
    const int bh = b * NH + h;
    const int tid = threadIdx.x;
    const int lane = tid & 63, wave = tid >> 6;
    const size_t base = (size_t)(bh * 8 + d) * 16;
    float acc[4] = {0.f, 0.f, 0.f, 0.f};

    for (int q = tid; q < 768; q += 256) {
        float Sv = 0.f, T2v = 0.f, SLv = 0.f, Mv = -1e30f;
#pragma unroll
        for (int kq = 0; kq < 4; kq++) {
            Sv  += part[(base + 0 + kq) * 768 + q];
            T2v += part[(base + 4 + kq) * 768 + q];
            SLv += part[(base + 8 + kq) * 768 + q];
            Mv = fmaxf(Mv, part[(base + 12 + kq) * 768 + q]);
        }
        l_arr[(size_t)(bh * 8 + d) * 768 + q] = Sv;
        float inv = 1.0f / Sv;
        float hhi = T2v * inv * inv;
        float maxp = __expf(Mv) * inv;
        float ent = __logf(Sv) - SLv * inv;
        float var = (hhi - (1.0f / 768.0f)) * (1.0f / 767.0f);
        acc[0] += var; acc[1] += maxp; acc[2] += ent; acc[3] += hhi;
    }
    __shared__ float red[4][4];
#pragma unroll
    for (int st = 0; st < 4; st++) {
        float a = acc[st];
#pragma unroll
        for (int off = 32; off > 0; off >>= 1) a += __shfl_xor(a, off, 64);
        acc[st] = a;
    }
    if (lane == 0) {
#pragma unroll
        for (int st = 0; st < 4; st++) red[wave][st] = acc[st];
    }
    __syncthreads();
    if (tid == 0) {
#pragma unroll
        for (int st = 0; st < 4; st++)
            part2[(size_t)(bd * 12 + h) * 4 + st] =
                red[0][st] + red[1][st] + red[2][st] + red[3][st];
    }
}

// ---------------------------------------------------------------------------
// K3b: sum over h, min-max norm over d, softmax(2.5*score) -> weights[b][d].
// ---------------------------------------------------------------------------
__global__ __launch_bounds__(64) void k3_weights(
    const float* __restrict__ part2, float* __restrict__ wgt)
{
    __shared__ float stats_l[64];       // [b][d][st]
    const int tid = threadIdx.x;
    {
        const int bd = tid >> 2, st = tid & 3;
        float s = 0.f;
#pragma unroll
        for (int h = 0; h < 12; h++) s += part2[(size_t)(bd * 12 + h) * 4 + st];
        stats_l[tid] = s * (1.0f / 9216.0f);
    }
    __syncthreads();
    if (tid == 0) {
        for (int b = 0; b < BATCH; b++) {
            float v[4][8];
            for (int st = 0; st < 4; st++)
                for (int d = 0; d < 8; d++) v[st][d] = stats_l[(b * 8 + d) * 4 + st];
            float nrm[4][8];
            for (int st = 0; st < 4; st++) {
                float mn = v[st][0], mx = v[st][0];
                for (int d = 1; d < 8; d++) { mn = fminf(mn, v[st][d]); mx = fmaxf(mx, v[st][d]); }
                float rng = fmaxf(mx - mn, 1e-12f);
                for (int d = 0; d < 8; d++) nrm[st][d] = (v[st][d] - mn) / rng;
            }
            float sc[8];
            for (int d = 0; d < 8; d++)
                sc[d] = 0.5f * nrm[0][d] + 0.3f * nrm[1][d] + 0.2f * nrm[3][d] - 0.4f * nrm[2][d];
            float m = 2.5f * sc[0];
            for (int d = 1; d < 8; d++) m = fmaxf(m, 2.5f * sc[d]);
            float e8[8]; float ssum = 0.f;
            for (int d = 0; d < 8; d++) { e8[d] = __expf(2.5f * sc[d] - m); ssum += e8[d]; }
            for (int d = 0; d < 8; d++) wgt[b * ND + d] = e8[d] / ssum;
        }
    }
}

// ---------------------------------------------------------------------------
// K4: attn4 ONLY (no atomics / cross-block combine; round-3 lesson: cross-XCD
// atomic hotspotting caused a 16x HBM write storm). Block = (bh, 64-q tile,
// k-quarter of 192), 32-kk staged K tiles.
// ---------------------------------------------------------------------------
__global__ __launch_bounds__(256) void k4_attn(
    const float* __restrict__ qw, const float* __restrict__ kw,
    const float* __restrict__ mask,
    const float* __restrict__ l_arr, const float* __restrict__ wgt,
    float* __restrict__ out_a4)
{
    __shared__ float k_lds[32 * 64];
    __shared__ float a4_lds[4][16 * 36];
    __shared__ float m_lds[32];
    const int tid = threadIdx.x;
    const int lane = tid & 63, w = tid >> 6;
    const int qr = lane >> 3, d = lane & 7;
    const int blk = blockIdx.x;
    const int kq = blk & 3;
    const int t2 = blk >> 2;
    const int bh = t2 / 12;
    const int q0 = (t2 % 12) * 64;
    const int b = bh / NH;
    const int qw0 = q0 + w * 16;

    float qf[2][8];
    float c0[2];
#pragma unroll
    for (int qq = 0; qq < 2; qq++) {
        int row = qw0 + qr + qq * 8;
        const float* qp = &qw[((size_t)bh * L_SEQ + row) * DH + d * 8];
        *(float4*)&qf[qq][0] = *(const float4*)qp;
        *(float4*)&qf[qq][4] = *(const float4*)(qp + 4);
        c0[qq] = wgt[b * ND + d] / l_arr[(size_t)(bh * 8 + d) * 768 + row];
    }

    const int kb0 = kq * 192;
    for (int c = 0; c < 6; c++) {
        const int kb = kb0 + c * 32;
        __syncthreads();
        {
            const float* ksrc = &kw[((size_t)bh * L_SEQ + kb) * DH];
#pragma unroll
            for (int i = 0; i < 2; i++) {
                int f = tid + 256 * i;
                *(float4*)&k_lds[f * 4] = *(const float4*)&ksrc[f * 4];
            }
            if (tid < 32) m_lds[tid] = mask[b * L_SEQ + kb + tid];
        }
        __syncthreads();

#pragma unroll
        for (int kk2 = 0; kk2 < 32; kk2 += 2) {
            float a4v[2][2];
#pragma unroll
            for (int u = 0; u < 2; u++) {
                int kk = kk2 + u;
                float kv[8];
                *(float4*)&kv[0] = *(const float4*)&k_lds[kk * 64 + d * 8];
                *(float4*)&kv[4] = *(const float4*)&k_lds[kk * 64 + d * 8 + 4];
                float mval = m_lds[kk];
#pragma unroll
                for (int qq = 0; qq < 2; qq++) {
                    float s = 0.f;
#pragma unroll
                    for (int t = 0; t < 8; t++) s = fmaf(qf[qq][t], kv[t], s);
                    s = fmaf(s, RSQRT8, mval);
                    a4v[u][qq] = c0[qq] * __expf(s);
                }
            }
#pragma unroll
            for (int u = 0; u < 2; u++)
#pragma unroll
                for (int qq = 0; qq < 2; qq++) {
                    float a = a4v[u][qq];
                    a += __shfl_xor(a, 1, 64);
                    a += __shfl_xor(a, 2, 64);
                    a += __shfl_xor(a, 4, 64);
                    a4v[u][qq] = a;
                }
#pragma unroll
            for (int u = 0; u < 2; u++) {
                int kk = kk2 + u;
                if (d < 2)
                    a4_lds[w][(qr + d * 8) * 36 + kk] = (d == 0) ? a4v[u][0] : a4v[u][1];
            }
        }
#pragma unroll
        for (int i = 0; i < 2; i++) {
            int f = lane + 64 * i;
            int row = f >> 3, c4 = (f & 7) * 4;
            *(float4*)&out_a4[((size_t)bh * L_SEQ + qw0 + row) * L_SEQ + kb + c4] =
                *(float4*)&a4_lds[w][row * 36 + c4];
        }
    }
}

// ---------------------------------------------------------------------------
// K5: ctx = attn4 @ V, reading attn4 back from d_out (L2/LLC-resident).
// V staged in NATURAL [kk][dh] layout (straight copy), lane=dh reads
// v_lds[kk*64+lane] -> consecutive lanes, 2 lanes/bank = conflict-free
// (round 4's [dh][kk] stride-68 layout was an 8-way bank conflict, 6.2M
// SQ_LDS_BANK_CONFLICT). Block = (bh, 16-q tile); wave = 4 q rows; a4 row
// loads are wave-uniform float4 (4 independent per step for L2-latency ILP).
// ROUND-6 FIX: grid must be 24*48 = 1152 (round 5 launched 576 -> batch 1
// never computed). No atomics; out_ctx written exactly once.
// ---------------------------------------------------------------------------
__global__ __launch_bounds__(256) void k5_ctx(
    const float* __restrict__ vw, const float* __restrict__ out_a4,
    float* __restrict__ out_ctx)
{
    __shared__ float v_lds[64 * 64];    // [kk][dh] natural layout, 16 KB
    const int tid = threadIdx.x;
    const int lane = tid & 63, w = tid >> 6;
    const int blk = blockIdx.x;         // bh*48 + qtile
    const int bh = blk / 48;
    const int q0 = (blk % 48) * 16;
    const int b = bh / NH, h = bh % NH;
    const int r0 = w * 4;

    const float* a4base = &out_a4[((size_t)bh * L_SEQ + q0 + r0) * L_SEQ];

    float ctx[4] = {0.f, 0.f, 0.f, 0.f};

    for (int c = 0; c < 12; c++) {
        const int kb = c * 64;
        __syncthreads();
        {   // stage V chunk, same layout as global: coalesced, conflict-free
            const float* vsrc = &vw[((size_t)bh * L_SEQ + kb) * DH];
#pragma unroll
            for (int i = 0; i < 4; i++) {
                int f = tid + 256 * i;
                *(float4*)&v_lds[f * 4] = *(const float4*)&vsrc[f * 4];
            }
        }
        __syncthreads();
#pragma unroll 4
        for (int kk4 = 0; kk4 < 16; kk4++) {
            float a4r[4][4];
            // 4 independent wave-uniform 16B loads (pipeline across L2 latency)
#pragma unroll
            for (int r = 0; r < 4; r++)
                *(float4*)&a4r[r][0] =
                    *(const float4*)&a4base[(size_t)r * L_SEQ + kb + kk4 * 4];
#pragma unroll
            for (int u = 0; u < 4; u++) {
                float vv = v_lds[(kk4 * 4 + u) * 64 + lane];
                ctx[0] = fmaf(a4r[0][u], vv, ctx[0]);
                ctx[1] = fmaf(a4r[1][u], vv, ctx[1]);
                ctx[2] = fmaf(a4r[2][u], vv, ctx[2]);
                ctx[3] = fmaf(a4r[3][u], vv, ctx[3]);
            }
        }
    }
#pragma unroll
    for (int r = 0; r < 4; r++)
        out_ctx[((size_t)b * L_SEQ + q0 + r0 + r) * EMB + h * DH + lane] = ctx[r];
}

// ---------------------------------------------------------------------------
extern "C" void kernel_launch(void* const* d_in, const int* in_sizes, int n_in,
                              void* d_out, int out_size, void* d_ws, size_t ws_size,
                              hipStream_t stream)
{
    const float* hs   = (const float*)d_in[0];
    const float* mask = (const float*)d_in[1];
    const float* Wq   = (const float*)d_in[2];
    const float* bq   = (const float*)d_in[3];
    const float* Wk   = (const float*)d_in[4];
    const float* bk   = (const float*)d_in[5];
    const float* Wv   = (const float*)d_in[6];
    const float* bv   = (const float*)d_in[7];

    float* ws = (float*)d_ws;
    float* qw = ws + OFF_Q;
    float* kw = ws + OFF_K;
    float* vw = ws + OFF_V;
    float* l_arr = ws + OFF_L;
    float* part  = ws + OFF_PART;
    float* part2 = ws + OFF_P2;
    float* wgt   = ws + OFF_W;

    float* out_ctx = (float*)d_out;                                  // [B, L, 768]
    float* out_a4  = (float*)d_out + (size_t)BATCH * L_SEQ * EMB;    // [B, H, L, L]

    k1_qkv<<<dim3(12, 24, 3), 256, 0, stream>>>(hs, Wq, bq, Wk, bk, Wv, bv, qw, kw, vw);
    k2_stats<<<dim3(1152), 256, 0, stream>>>(qw, kw, mask, part);
    k3_reduce<<<dim3(192), 256, 0, stream>>>(part, l_arr, part2);
    k3_weights<<<dim3(1), 64, 0, stream>>>(part2, wgt);
    k4_attn<<<dim3(1152), 256, 0, stream>>>(qw, kw, mask, l_arr, wgt, out_a4);
    k5_ctx<<<dim3(1152), 256, 0, stream>>>(vw, out_a4, out_ctx);
}

// Round 7
// 366.693 us; speedup vs baseline: 3.3029x; 1.2178x over previous
//
#include <hip/hip_runtime.h>

// Problem constants (fixed by reference setup_inputs)
#define BATCH 2
#define L_SEQ 768
#define NH 12
#define DH 64
#define ND 8
#define EMB 768
#define RSQRT8 0.35355339059327373f

// ws layout (floats). Total 6,046,480 floats = 24.2 MB
#define OFF_Q    0
#define OFF_K    1179648
#define OFF_V    2359296
#define OFF_L    3538944   // S0 per (bh,d,q): 147456
#define OFF_PART 3686400   // partial stats [bh*8+d][st*4+kq][q]: 2359296
#define OFF_P2   6045696   // per-(b,d,h) stat sums [bd][h][st]: 768
#define OFF_W    6046464   // weights [b][d]: 16

// ---------------------------------------------------------------------------
// K1: fused QKV projection. C = hs @ W + b, scattered to [b][h][l][64] layout.
// 64x64 tiles, 4x4 per thread, fp32 (no fp32 MFMA on CDNA4).
// ---------------------------------------------------------------------------
__global__ __launch_bounds__(256) void k1_qkv(
    const float* __restrict__ hs,
    const float* __restrict__ Wq, const float* __restrict__ bq,
    const float* __restrict__ Wk, const float* __restrict__ bk,
    const float* __restrict__ Wv, const float* __restrict__ bvp,
    float* __restrict__ qw, float* __restrict__ kw, float* __restrict__ vw)
{
    __shared__ float AsT[64][68];
    __shared__ float Bs[64][68];
    const int tid = threadIdx.x;
    const int tx = tid & 15, ty = tid >> 4;
    const int bx = blockIdx.x, by = blockIdx.y, gz = blockIdx.z;
    const float* W    = (gz == 0) ? Wq : (gz == 1 ? Wk : Wv);
    const float* bias = (gz == 0) ? bq : (gz == 1 ? bk : bvp);
    float* dst        = (gz == 0) ? qw : (gz == 1 ? kw : vw);

    const int ldc = tx * 4;

    float acc[4][4];
#pragma unroll
    for (int i = 0; i < 4; i++)
#pragma unroll
        for (int j = 0; j < 4; j++) acc[i][j] = 0.f;

    for (int k0 = 0; k0 < EMB; k0 += 64) {
        __syncthreads();
#pragma unroll
        for (int i = 0; i < 4; i++) {
            int r = ty + 16 * i;
            float4 a = *(const float4*)&hs[(size_t)(by * 64 + r) * EMB + k0 + ldc];
            AsT[ldc + 0][r] = a.x; AsT[ldc + 1][r] = a.y;
            AsT[ldc + 2][r] = a.z; AsT[ldc + 3][r] = a.w;
            *(float4*)&Bs[r][ldc] =
                *(const float4*)&W[(size_t)(k0 + r) * EMB + bx * 64 + ldc];
        }
        __syncthreads();
#pragma unroll 8
        for (int kk = 0; kk < 64; kk++) {
            float av[4], bb[4];
            *(float4*)av = *(const float4*)&AsT[kk][ty * 4];
            *(float4*)bb = *(const float4*)&Bs[kk][tx * 4];
#pragma unroll
            for (int i = 0; i < 4; i++)
#pragma unroll
                for (int j = 0; j < 4; j++)
                    acc[i][j] = fmaf(av[i], bb[j], acc[i][j]);
        }
    }

#pragma unroll
    for (int i = 0; i < 4; i++) {
        int m = by * 64 + ty * 4 + i;
        int b2 = m / L_SEQ, l = m % L_SEQ;
        float o[4];
#pragma unroll
        for (int j = 0; j < 4; j++) o[j] = acc[i][j] + bias[bx * 64 + tx * 4 + j];
        *(float4*)&dst[((size_t)(b2 * NH + bx) * L_SEQ + l) * DH + tx * 4] = *(float4*)o;
    }
}

// ---------------------------------------------------------------------------
// K2: softmax partial stats. Block = (bh, 64-q tile, k-quarter of 192).
// 4 waves x 16 q rows; lane = (qr, d); K chunk [64k][64dim] staged in LDS.
// ---------------------------------------------------------------------------
__global__ __launch_bounds__(256) void k2_stats(
    const float* __restrict__ qw, const float* __restrict__ kw,
    const float* __restrict__ mask, float* __restrict__ part)
{
    __shared__ float k_lds[64 * 64];
    __shared__ float m_lds[64];
    const int tid = threadIdx.x;
    const int lane = tid & 63, w = tid >> 6;
    const int qr = lane >> 3, d = lane & 7;
    const int blk = blockIdx.x;
    const int kq = blk & 3;
    const int t2 = blk >> 2;            // 0..287
    const int bh = t2 / 12;
    const int q0 = (t2 % 12) * 64;
    const int b = bh / NH;
    const int qw0 = q0 + w * 16;

    float qf[2][8];
#pragma unroll
    for (int qq = 0; qq < 2; qq++) {
        const float* qp = &qw[((size_t)bh * L_SEQ + qw0 + qr + qq * 8) * DH + d * 8];
        *(float4*)&qf[qq][0] = *(const float4*)qp;
        *(float4*)&qf[qq][4] = *(const float4*)(qp + 4);
    }
    float S[2] = {0.f, 0.f}, T2[2] = {0.f, 0.f}, SL[2] = {0.f, 0.f};
    float M[2] = {-1e30f, -1e30f};

    const int kb0 = kq * 192;
    for (int c = 0; c < 3; c++) {
        const int kb = kb0 + c * 64;
        __syncthreads();
        {
            const float* src = &kw[((size_t)bh * L_SEQ + kb) * DH];
#pragma unroll
            for (int i = 0; i < 4; i++) {
                int f = tid + 256 * i;
                *(float4*)&k_lds[f * 4] = *(const float4*)&src[f * 4];
            }
            if (tid < 64) m_lds[tid] = mask[b * L_SEQ + kb + tid];
        }
        __syncthreads();
#pragma unroll 4
        for (int kk = 0; kk < 64; kk++) {
            float kv[8];
            *(float4*)&kv[0] = *(const float4*)&k_lds[kk * 64 + d * 8];
            *(float4*)&kv[4] = *(const float4*)&k_lds[kk * 64 + d * 8 + 4];
            float mval = m_lds[kk];
#pragma unroll
            for (int qq = 0; qq < 2; qq++) {
                float s = 0.f;
#pragma unroll
                for (int t = 0; t < 8; t++) s = fmaf(qf[qq][t], kv[t], s);
                s = fmaf(s, RSQRT8, mval);
                float e = __expf(s);
                S[qq] += e;
                T2[qq] = fmaf(e, e, T2[qq]);
                SL[qq] = fmaf(s, e, SL[qq]);
                M[qq] = fmaxf(M[qq], s);
            }
        }
    }
#pragma unroll
    for (int qq = 0; qq < 2; qq++) {
        int q = qw0 + qr + qq * 8;
        size_t base = (size_t)(bh * 8 + d) * 16;
        part[(base + 0 + kq) * 768 + q] = S[qq];
        part[(base + 4 + kq) * 768 + q] = T2[qq];
        part[(base + 8 + kq) * 768 + q] = SL[qq];
        part[(base + 12 + kq) * 768 + q] = M[qq];
    }
}

// ---------------------------------------------------------------------------
// K3a: per-(b,d,h) combine of k-quarters -> row stats -> l_arr + stat sums.
// ---------------------------------------------------------------------------
__global__ __launch_bounds__(256) void k3_reduce(
    const float* __restrict__ part, float* __restrict__ l_arr,
    float* __restrict__ part2)
{
    const int bdh = blockIdx.x;         // ((b*8+d)*12+h)
    const int bd = bdh / 12, h = bdh % 12;
    const int b = bd >> 3, d = bd & 7;
    const int bh = b * NH + h;
    const int tid = threadIdx.x;
    const int lane = tid & 63, wave = tid >> 6;
    const size_t base = (size_t)(bh * 8 + d) * 16;
    float acc[4] = {0.f, 0.f, 0.f, 0.f};

    for (int q = tid; q < 768; q += 256) {
        float Sv = 0.f, T2v = 0.f, SLv = 0.f, Mv = -1e30f;
#pragma unroll
        for (int kq = 0; kq < 4; kq++) {
            Sv  += part[(base + 0 + kq) * 768 + q];
            T2v += part[(base + 4 + kq) * 768 + q];
            SLv += part[(base + 8 + kq) * 768 + q];
            Mv = fmaxf(Mv, part[(base + 12 + kq) * 768 + q]);
        }
        l_arr[(size_t)(bh * 8 + d) * 768 + q] = Sv;
        float inv = 1.0f / Sv;
        float hhi = T2v * inv * inv;
        float maxp = __expf(Mv) * inv;
        float ent = __logf(Sv) - SLv * inv;
        float var = (hhi - (1.0f / 768.0f)) * (1.0f / 767.0f);
        acc[0] += var; acc[1] += maxp; acc[2] += ent; acc[3] += hhi;
    }
    __shared__ float red[4][4];
#pragma unroll
    for (int st = 0; st < 4; st++) {
        float a = acc[st];
#pragma unroll
        for (int off = 32; off > 0; off >>= 1) a += __shfl_xor(a, off, 64);
        acc[st] = a;
    }
    if (lane == 0) {
#pragma unroll
        for (int st = 0; st < 4; st++) red[wave][st] = acc[st];
    }
    __syncthreads();
    if (tid == 0) {
#pragma unroll
        for (int st = 0; st < 4; st++)
            part2[(size_t)(bd * 12 + h) * 4 + st] =
                red[0][st] + red[1][st] + red[2][st] + red[3][st];
    }
}

// ---------------------------------------------------------------------------
// K3b: sum over h, min-max norm over d, softmax(2.5*score) -> weights[b][d].
// ---------------------------------------------------------------------------
__global__ __launch_bounds__(64) void k3_weights(
    const float* __restrict__ part2, float* __restrict__ wgt)
{
    __shared__ float stats_l[64];       // [b][d][st]
    const int tid = threadIdx.x;
    {
        const int bd = tid >> 2, st = tid & 3;
        float s = 0.f;
#pragma unroll
        for (int h = 0; h < 12; h++) s += part2[(size_t)(bd * 12 + h) * 4 + st];
        stats_l[tid] = s * (1.0f / 9216.0f);
    }
    __syncthreads();
    if (tid == 0) {
        for (int b = 0; b < BATCH; b++) {
            float v[4][8];
            for (int st = 0; st < 4; st++)
                for (int d = 0; d < 8; d++) v[st][d] = stats_l[(b * 8 + d) * 4 + st];
            float nrm[4][8];
            for (int st = 0; st < 4; st++) {
                float mn = v[st][0], mx = v[st][0];
                for (int d = 1; d < 8; d++) { mn = fminf(mn, v[st][d]); mx = fmaxf(mx, v[st][d]); }
                float rng = fmaxf(mx - mn, 1e-12f);
                for (int d = 0; d < 8; d++) nrm[st][d] = (v[st][d] - mn) / rng;
            }
            float sc[8];
            for (int d = 0; d < 8; d++)
                sc[d] = 0.5f * nrm[0][d] + 0.3f * nrm[1][d] + 0.2f * nrm[3][d] - 0.4f * nrm[2][d];
            float m = 2.5f * sc[0];
            for (int d = 1; d < 8; d++) m = fmaxf(m, 2.5f * sc[d]);
            float e8[8]; float ssum = 0.f;
            for (int d = 0; d < 8; d++) { e8[d] = __expf(2.5f * sc[d] - m); ssum += e8[d]; }
            for (int d = 0; d < 8; d++) wgt[b * ND + d] = e8[d] / ssum;
        }
    }
}

// ---------------------------------------------------------------------------
// K4: attn4 ONLY (no atomics / cross-block combine; round-3 lesson: cross-XCD
// atomic hotspotting caused a 16x HBM write storm). Block = (bh, 64-q tile,
// k-quarter of 192), 32-kk staged K tiles.
// ---------------------------------------------------------------------------
__global__ __launch_bounds__(256) void k4_attn(
    const float* __restrict__ qw, const float* __restrict__ kw,
    const float* __restrict__ mask,
    const float* __restrict__ l_arr, const float* __restrict__ wgt,
    float* __restrict__ out_a4)
{
    __shared__ float k_lds[32 * 64];
    __shared__ float a4_lds[4][16 * 36];
    __shared__ float m_lds[32];
    const int tid = threadIdx.x;
    const int lane = tid & 63, w = tid >> 6;
    const int qr = lane >> 3, d = lane & 7;
    const int blk = blockIdx.x;
    const int kq = blk & 3;
    const int t2 = blk >> 2;
    const int bh = t2 / 12;
    const int q0 = (t2 % 12) * 64;
    const int b = bh / NH;
    const int qw0 = q0 + w * 16;

    float qf[2][8];
    float c0[2];
#pragma unroll
    for (int qq = 0; qq < 2; qq++) {
        int row = qw0 + qr + qq * 8;
        const float* qp = &qw[((size_t)bh * L_SEQ + row) * DH + d * 8];
        *(float4*)&qf[qq][0] = *(const float4*)qp;
        *(float4*)&qf[qq][4] = *(const float4*)(qp + 4);
        c0[qq] = wgt[b * ND + d] / l_arr[(size_t)(bh * 8 + d) * 768 + row];
    }

    const int kb0 = kq * 192;
    for (int c = 0; c < 6; c++) {
        const int kb = kb0 + c * 32;
        __syncthreads();
        {
            const float* ksrc = &kw[((size_t)bh * L_SEQ + kb) * DH];
#pragma unroll
            for (int i = 0; i < 2; i++) {
                int f = tid + 256 * i;
                *(float4*)&k_lds[f * 4] = *(const float4*)&ksrc[f * 4];
            }
            if (tid < 32) m_lds[tid] = mask[b * L_SEQ + kb + tid];
        }
        __syncthreads();

#pragma unroll
        for (int kk2 = 0; kk2 < 32; kk2 += 2) {
            float a4v[2][2];
#pragma unroll
            for (int u = 0; u < 2; u++) {
                int kk = kk2 + u;
                float kv[8];
                *(float4*)&kv[0] = *(const float4*)&k_lds[kk * 64 + d * 8];
                *(float4*)&kv[4] = *(const float4*)&k_lds[kk * 64 + d * 8 + 4];
                float mval = m_lds[kk];
#pragma unroll
                for (int qq = 0; qq < 2; qq++) {
                    float s = 0.f;
#pragma unroll
                    for (int t = 0; t < 8; t++) s = fmaf(qf[qq][t], kv[t], s);
                    s = fmaf(s, RSQRT8, mval);
                    a4v[u][qq] = c0[qq] * __expf(s);
                }
            }
#pragma unroll
            for (int u = 0; u < 2; u++)
#pragma unroll
                for (int qq = 0; qq < 2; qq++) {
                    float a = a4v[u][qq];
                    a += __shfl_xor(a, 1, 64);
                    a += __shfl_xor(a, 2, 64);
                    a += __shfl_xor(a, 4, 64);
                    a4v[u][qq] = a;
                }
#pragma unroll
            for (int u = 0; u < 2; u++) {
                int kk = kk2 + u;
                if (d < 2)
                    a4_lds[w][(qr + d * 8) * 36 + kk] = (d == 0) ? a4v[u][0] : a4v[u][1];
            }
        }
#pragma unroll
        for (int i = 0; i < 2; i++) {
            int f = lane + 64 * i;
            int row = f >> 3, c4 = (f & 7) * 4;
            *(float4*)&out_a4[((size_t)bh * L_SEQ + qw0 + row) * L_SEQ + kb + c4] =
                *(float4*)&a4_lds[w][row * 36 + c4];
        }
    }
}

// ---------------------------------------------------------------------------
// K5 (round-7 rewrite): ctx = attn4 @ V as an LDS-tiled GEMM.
// ROUND-6 LESSON: wave-uniform global loads move 16 B/instr (vs 1024 B for
// lane-spread) -> latency wall (148us, 352 GB/s, VALUBusy 24%). Fix: stage
// the a4 tile in LDS via lane-parallel coalesced loads.
// Block = (bh, 32-q tile), grid 576. K-chunks of 64:
//   a4 tile [32][68pad] (8.5 KB) + V tile [64][64] (16 KB), both staged with
//   float4 lane-parallel loads. Thread = 2 rows x 4 cols; per kk4 step:
//   2 a4 ds_read_b128 (pad-68 -> 4 distinct bank-groups) + 4 V ds_read_b128
//   (16 addrs x 4-way broadcast) -> 32 FMAs. LDS 72cyc vs VALU 64cyc/wave.
// No atomics; out_ctx written exactly once; k-ascending sum order preserved.
// ---------------------------------------------------------------------------
__global__ __launch_bounds__(256) void k5_ctx(
    const float* __restrict__ vw, const float* __restrict__ out_a4,
    float* __restrict__ out_ctx)
{
    __shared__ float a4_lds[32 * 68];   // [row][kk], pad 68
    __shared__ float v_lds[64 * 64];    // [kk][dh] natural layout
    const int tid = threadIdx.x;
    const int lane = tid & 63, w = tid >> 6;
    const int ty = (lane >> 4);         // 0..3
    const int tx = lane & 15;           // 0..15 -> cols tx*4..+3
    const int rbase = w * 8 + ty * 2;   // 2 rows per thread
    const int blk = blockIdx.x;         // bh*24 + qtile
    const int bh = blk / 24;
    const int q0 = (blk % 24) * 32;
    const int b = bh / NH, h = bh % NH;

    const float* a4src = &out_a4[((size_t)bh * L_SEQ + q0) * L_SEQ];

    float acc[2][4];
#pragma unroll
    for (int qq = 0; qq < 2; qq++)
#pragma unroll
        for (int j = 0; j < 4; j++) acc[qq][j] = 0.f;

    for (int c = 0; c < 12; c++) {
        const int kb = c * 64;
        __syncthreads();
        {   // stage a4 tile [32 rows][64 k] -> a4_lds[row*68 + k] (2 float4/thread)
#pragma unroll
            for (int i = 0; i < 2; i++) {
                int f = tid + 256 * i;          // 0..511
                int row = f >> 4, col = (f & 15) * 4;
                *(float4*)&a4_lds[row * 68 + col] =
                    *(const float4*)&a4src[(size_t)row * L_SEQ + kb + col];
            }
            // stage V chunk [64 k][64 dh], straight copy (4 float4/thread)
            const float* vsrc = &vw[((size_t)bh * L_SEQ + kb) * DH];
#pragma unroll
            for (int i = 0; i < 4; i++) {
                int f = tid + 256 * i;
                *(float4*)&v_lds[f * 4] = *(const float4*)&vsrc[f * 4];
            }
        }
        __syncthreads();
#pragma unroll
        for (int kk4 = 0; kk4 < 16; kk4++) {
            float af[2][4];
            *(float4*)&af[0][0] = *(const float4*)&a4_lds[(rbase + 0) * 68 + kk4 * 4];
            *(float4*)&af[1][0] = *(const float4*)&a4_lds[(rbase + 1) * 68 + kk4 * 4];
#pragma unroll
            for (int u = 0; u < 4; u++) {
                float4 vv = *(const float4*)&v_lds[(kk4 * 4 + u) * 64 + tx * 4];
#pragma unroll
                for (int qq = 0; qq < 2; qq++) {
                    acc[qq][0] = fmaf(af[qq][u], vv.x, acc[qq][0]);
                    acc[qq][1] = fmaf(af[qq][u], vv.y, acc[qq][1]);
                    acc[qq][2] = fmaf(af[qq][u], vv.z, acc[qq][2]);
                    acc[qq][3] = fmaf(af[qq][u], vv.w, acc[qq][3]);
                }
            }
        }
    }
#pragma unroll
    for (int qq = 0; qq < 2; qq++)
        *(float4*)&out_ctx[((size_t)b * L_SEQ + q0 + rbase + qq) * EMB + h * DH + tx * 4] =
            *(float4*)&acc[qq][0];
}

// ---------------------------------------------------------------------------
extern "C" void kernel_launch(void* const* d_in, const int* in_sizes, int n_in,
                              void* d_out, int out_size, void* d_ws, size_t ws_size,
                              hipStream_t stream)
{
    const float* hs   = (const float*)d_in[0];
    const float* mask = (const float*)d_in[1];
    const float* Wq   = (const float*)d_in[2];
    const float* bq   = (const float*)d_in[3];
    const float* Wk   = (const float*)d_in[4];
    const float* bk   = (const float*)d_in[5];
    const float* Wv   = (const float*)d_in[6];
    const float* bv   = (const float*)d_in[7];

    float* ws = (float*)d_ws;
    float* qw = ws + OFF_Q;
    float* kw = ws + OFF_K;
    float* vw = ws + OFF_V;
    float* l_arr = ws + OFF_L;
    float* part  = ws + OFF_PART;
    float* part2 = ws + OFF_P2;
    float* wgt   = ws + OFF_W;

    float* out_ctx = (float*)d_out;                                  // [B, L, 768]
    float* out_a4  = (float*)d_out + (size_t)BATCH * L_SEQ * EMB;    // [B, H, L, L]

    k1_qkv<<<dim3(12, 24, 3), 256, 0, stream>>>(hs, Wq, bq, Wk, bk, Wv, bv, qw, kw, vw);
    k2_stats<<<dim3(1152), 256, 0, stream>>>(qw, kw, mask, part);
    k3_reduce<<<dim3(192), 256, 0, stream>>>(part, l_arr, part2);
    k3_weights<<<dim3(1), 64, 0, stream>>>(part2, wgt);
    k4_attn<<<dim3(1152), 256, 0, stream>>>(qw, kw, mask, l_arr, wgt, out_a4);
    k5_ctx<<<dim3(576), 256, 0, stream>>>(vw, out_a4, out_ctx);
}